// Round 2
// baseline (278.899 us; speedup 1.0000x reference)
//
#include <hip/hip_runtime.h>
#include <math.h>

#define NTHG 8            // Gauss-Legendre theta points (exact to degree 15 >= 12 needed)
#define NPHG 16           // uniform phi points (exact for |m| < 16, need <= 12)
#define NG   (NTHG*NPHG)  // 128 grid points
#define YP   28           // Y row stride, padded 25->28 for float4 alignment
#define L2C  25
#define CCH  128
#define PADR 144          // padded LDS row stride: 4 quarters x 36 floats

static __device__ __forceinline__ int lof_of(int i) {
  return (i >= 16) ? 4 : (i >= 9) ? 3 : (i >= 4) ? 2 : (i >= 1) ? 1 : 0;
}
static __device__ __forceinline__ int pidx(int c) {   // padded channel index
  return (c >> 5) * 36 + (c & 31);
}

// ---------------------------------------------------------------------------
// Build Y[g][i], Yw[g][i] tables (float, stride YP) + vec0[d] = b1[d] +
// sum_c norm_b[c]*w1[0][c][d] in workspace. Pure device compute, capture-safe.
// ws layout: [0, NG*YP) Y | [NG*YP, 2*NG*YP) Yw | [2*NG*YP, +CCH) vec0
// ---------------------------------------------------------------------------
__global__ void init_tables_kernel(float* __restrict__ ws,
                                   const float* __restrict__ norm_b,
                                   const float* __restrict__ w1,
                                   const float* __restrict__ b1) {
  __shared__ double ct[NTHG], wt[NTHG];
  const int t = threadIdx.x;
  const double PI = 3.14159265358979323846264338327950288;
  if (t < NTHG) {
    // Newton iteration for roots of P_8 (Gauss-Legendre)
    double xx = cos(PI * (t + 0.75) / (NTHG + 0.5));
    double dp = 1.0;
    for (int it = 0; it < 64; ++it) {
      double p0 = 1.0, p1 = xx;
      for (int k = 2; k <= NTHG; ++k) {
        double p2 = ((2.0*k - 1.0)*xx*p1 - (k - 1.0)*p0) / (double)k;
        p0 = p1; p1 = p2;
      }
      dp = NTHG * (xx*p1 - p0) / (xx*xx - 1.0);
      xx -= p1 / dp;
    }
    { double p0 = 1.0, p1 = xx;
      for (int k = 2; k <= NTHG; ++k) {
        double p2 = ((2.0*k - 1.0)*xx*p1 - (k - 1.0)*p0) / (double)k;
        p0 = p1; p1 = p2;
      }
      dp = NTHG * (xx*p1 - p0) / (xx*xx - 1.0);
    }
    ct[t] = xx;
    wt[t] = 2.0 / ((1.0 - xx*xx) * dp * dp);
  }
  __syncthreads();
  const double FACT[9] = {1,1,2,6,24,120,720,5040,40320};
  for (int e = t; e < NG*YP; e += blockDim.x) {
    const int g = e / YP, i = e % YP;
    float yv = 0.f, ywv = 0.f;
    if (i < L2C) {
      const int tt = g / NPHG, pp = g % NPHG;
      int l = 0; while ((l+1)*(l+1) <= i) ++l;
      const int m = i - l*l - l;
      const int am = m < 0 ? -m : m;
      const double x = ct[tt], st = sqrt(1.0 - x*x);
      double pmm = 1.0;
      for (int mm = 1; mm <= am; ++mm) pmm *= -(2.0*mm - 1.0) * st;
      double plm;
      if (l == am) plm = pmm;
      else {
        double pa = pmm, pb = (2.0*am + 1.0) * x * pmm;
        for (int ll = am + 2; ll <= l; ++ll) {
          double pc = ((2.0*ll - 1.0)*x*pb - (ll + am - 1.0)*pa) / (double)(ll - am);
          pa = pb; pb = pc;
        }
        plm = pb;
      }
      const double Nn = sqrt((2.0*l + 1.0)/(4.0*PI) * FACT[l-am]/FACT[l+am]);
      const double phi = 2.0*PI*pp/NPHG;
      double ang, pref;
      if (m == 0)      { ang = 1.0;          pref = 1.0; }
      else if (m > 0)  { ang = cos(m*phi);   pref = sqrt(2.0); }
      else             { ang = sin(am*phi);  pref = sqrt(2.0); }
      const double Y = pref * Nn * plm * ang;
      yv  = (float)Y;
      ywv = (float)(Y * wt[tt] * (2.0*PI/NPHG));
    }
    ws[e]         = yv;
    ws[NG*YP + e] = ywv;
  }
  // vec0[d] = b1[d] + sum_c norm_b[c] * w1[degree0][c][d]
  if (t < CCH) {
    float s = b1[t];
    for (int c = 0; c < CCH; ++c) s = fmaf(norm_b[c], w1[c*CCH + t], s);
    ws[2*NG*YP + t] = s;
  }
}

// block-wide sum over 256 threads (4 waves of 64)
__device__ __forceinline__ float block_sum(float v, float* scr, int t) {
#pragma unroll
  for (int o = 32; o > 0; o >>= 1) v += __shfl_down(v, o, 64);
  __syncthreads();              // protect scr from previous use
  if ((t & 63) == 0) scr[t >> 6] = v;
  __syncthreads();
  return scr[0] + scr[1] + scr[2] + scr[3];
}

// ---------------------------------------------------------------------------
// Linear1 with LayerNorm folded into the weights:
//   h[i,c] = (x[i,c] - [i==0]*mean0) * inv * norm_w[l,c]  (+norm_b[c] on l=0)
//   out[i,d] = sum_c h[i,c]*W[c,d] (+b1[d] on l=0)
//            = sum_c x[i,c]*w'[c,d] - [l==0]*mean0*sum_c w'[c,d] + [l==0]*vec0[d]
//   with w'[c,d] = inv*norm_w[l,c]*W[c,d];  vec0 = b1 + norm_b @ W0 (precomputed)
// 4-way c-split in lane bits 4-5, 2 outputs per thread, shfl_xor reduce.
// ---------------------------------------------------------------------------
template<int L>
__device__ __forceinline__ void lin1(const float* __restrict__ sA,  // raw x, padded
                                     float* __restrict__ sB,        // h out, padded
                                     const float* __restrict__ w1,
                                     const float* __restrict__ norm_w,
                                     const float* __restrict__ vec0,
                                     float inv, float mean0, int t) {
  constexpr int NC = 2*L + 1, I0 = L*L;
  const int dlo = (t & 15) | ((t >> 2) & 48);   // bits0-3 + (wave<<4)
  const int q   = (t >> 4) & 3;                 // quarter = lane bits 4-5
  float acc0[NC], acc1[NC], ae0 = 0.f, ae1 = 0.f;
#pragma unroll
  for (int j = 0; j < NC; ++j) { acc0[j] = 0.f; acc1[j] = 0.f; }
  const float* w  = w1 + L*CCH*CCH;
  const float* nw = norm_w + L*CCH;
  const int c0 = q * 32;
  for (int cc = 0; cc < 32; cc += 4) {
    const int c = c0 + cc;
    const float4 nw4 = *(const float4*)&nw[c];
    const float s0 = nw4.x*inv, s1 = nw4.y*inv, s2 = nw4.z*inv, s3 = nw4.w*inv;
    const float* wc = w + c*CCH;
    const float wa0 = wc[dlo]*s0,        wb0 = wc[dlo+64]*s0;
    const float wa1 = wc[CCH+dlo]*s1,    wb1 = wc[CCH+dlo+64]*s1;
    const float wa2 = wc[2*CCH+dlo]*s2,  wb2 = wc[2*CCH+dlo+64]*s2;
    const float wa3 = wc[3*CCH+dlo]*s3,  wb3 = wc[3*CCH+dlo+64]*s3;
    if (L == 0) { ae0 += (wa0+wa1)+(wa2+wa3); ae1 += (wb0+wb1)+(wb2+wb3); }
    const float* arow = sA + I0*PADR + q*36 + cc;
#pragma unroll
    for (int j = 0; j < NC; ++j) {
      const float4 a = *(const float4*)&arow[j*PADR];
      acc0[j] = fmaf(a.w,wa3, fmaf(a.z,wa2, fmaf(a.y,wa1, fmaf(a.x,wa0, acc0[j]))));
      acc1[j] = fmaf(a.w,wb3, fmaf(a.z,wb2, fmaf(a.y,wb1, fmaf(a.x,wb0, acc1[j]))));
    }
  }
#pragma unroll
  for (int j = 0; j < NC; ++j) {
    acc0[j] += __shfl_xor(acc0[j], 16, 64); acc0[j] += __shfl_xor(acc0[j], 32, 64);
    acc1[j] += __shfl_xor(acc1[j], 16, 64); acc1[j] += __shfl_xor(acc1[j], 32, 64);
  }
  if (L == 0) {
    ae0 += __shfl_xor(ae0, 16, 64); ae0 += __shfl_xor(ae0, 32, 64);
    ae1 += __shfl_xor(ae1, 16, 64); ae1 += __shfl_xor(ae1, 32, 64);
  }
  if (q == 0) {
#pragma unroll
    for (int j = 0; j < NC; ++j) {
      float r0 = acc0[j], r1 = acc1[j];
      if (L == 0) { r0 += vec0[dlo]    - mean0*ae0;
                    r1 += vec0[dlo+64] - mean0*ae1; }
      sB[(I0+j)*PADR + pidx(dlo)]    = r0;
      sB[(I0+j)*PADR + pidx(dlo+64)] = r1;
    }
  }
}

// Linear2 + bias(l=0) + residual(from LDS raw x) -> global out
template<int L>
__device__ __forceinline__ void lin2(const float* __restrict__ sB,  // y, padded
                                     const float* __restrict__ sA,  // raw x, padded
                                     const float* __restrict__ w2,
                                     const float* __restrict__ b2,
                                     float* __restrict__ gout, int t) {
  constexpr int NC = 2*L + 1, I0 = L*L;
  const int dlo = (t & 15) | ((t >> 2) & 48);
  const int q   = (t >> 4) & 3;
  float acc0[NC], acc1[NC];
#pragma unroll
  for (int j = 0; j < NC; ++j) { acc0[j] = 0.f; acc1[j] = 0.f; }
  const float* w = w2 + L*CCH*CCH;
  const int c0 = q * 32;
  for (int cc = 0; cc < 32; cc += 4) {
    const int c = c0 + cc;
    const float* wc = w + c*CCH;
    const float wa0 = wc[dlo],        wb0 = wc[dlo+64];
    const float wa1 = wc[CCH+dlo],    wb1 = wc[CCH+dlo+64];
    const float wa2 = wc[2*CCH+dlo],  wb2 = wc[2*CCH+dlo+64];
    const float wa3 = wc[3*CCH+dlo],  wb3 = wc[3*CCH+dlo+64];
    const float* arow = sB + I0*PADR + q*36 + cc;
#pragma unroll
    for (int j = 0; j < NC; ++j) {
      const float4 a = *(const float4*)&arow[j*PADR];
      acc0[j] = fmaf(a.w,wa3, fmaf(a.z,wa2, fmaf(a.y,wa1, fmaf(a.x,wa0, acc0[j]))));
      acc1[j] = fmaf(a.w,wb3, fmaf(a.z,wb2, fmaf(a.y,wb1, fmaf(a.x,wb0, acc1[j]))));
    }
  }
#pragma unroll
  for (int j = 0; j < NC; ++j) {
    acc0[j] += __shfl_xor(acc0[j], 16, 64); acc0[j] += __shfl_xor(acc0[j], 32, 64);
    acc1[j] += __shfl_xor(acc1[j], 16, 64); acc1[j] += __shfl_xor(acc1[j], 32, 64);
  }
  if (q == 0) {
#pragma unroll
    for (int j = 0; j < NC; ++j) {
      float r0 = acc0[j], r1 = acc1[j];
      if (L == 0) { r0 += b2[dlo]; r1 += b2[dlo+64]; }
      r0 += sA[(I0+j)*PADR + pidx(dlo)];     // residual: raw x kept in LDS
      r1 += sA[(I0+j)*PADR + pidx(dlo+64)];
      gout[(I0+j)*CCH + dlo]    = r0;
      gout[(I0+j)*CCH + dlo+64] = r1;
    }
  }
}

// ---------------------------------------------------------------------------
// Fully fused: (LN folded) Linear1 -> grid Gaunt self-TP -> Linear2 -> +res
// One block per node. LDS ~57.5 KB -> 2 blocks/CU.
// ---------------------------------------------------------------------------
__global__ __launch_bounds__(256, 2)
void fused_gaunt_kernel(const float* __restrict__ x,
                        const float* __restrict__ norm_w,
                        const float* __restrict__ w1,
                        const float* __restrict__ tp_w,
                        const float* __restrict__ w2,
                        const float* __restrict__ b2,
                        const float* __restrict__ ytab,
                        float* __restrict__ out) {
  __shared__ float sY [NG*YP];     // 14336 B
  __shared__ float sYw[NG*YP];     // 14336 B
  __shared__ float sA [L2C*PADR];  // 14400 B (raw x, padded quarters)
  __shared__ float sB [L2C*PADR];  // 14400 B (h / y)
  __shared__ float sScr[8];

  const int t = threadIdx.x;
  const int n = blockIdx.x;
  const float* xn = x   + (size_t)n * (L2C*CCH);
  float*       on = out + (size_t)n * (L2C*CCH);
  const float* vec0 = ytab + 2*NG*YP;

  // ---- stage: x -> sA (padded), Y tables -> LDS (float4, coalesced)
  for (int e = t; e < (L2C*CCH)/4; e += 256) {
    const int i = e >> 5, c = (e & 31) << 2;
    *(float4*)&sA[i*PADR + pidx(c)] = ((const float4*)xn)[e];
  }
  for (int e = t; e < (NG*YP)/4; e += 256) {
    ((float4*)sY )[e] = ((const float4*)ytab)[e];
    ((float4*)sYw)[e] = ((const float4*)ytab)[(NG*YP)/4 + e];
  }
  __syncthreads();

  // ---- LN statistics (no materialized LN pass; folded into lin1)
  // mean0 over l=0 channels; var = (sum x^2 - CCH*mean0^2) / (L2C*CCH)
  float v0 = (t < CCH) ? sA[pidx(t)] : 0.f;
  const float mean0 = block_sum(v0, sScr, t) * (1.f/CCH);
  float ss = 0.f;
  for (int e = t; e < L2C*CCH; e += 256) {
    const float val = sA[(e >> 7)*PADR + pidx(e & 127)];
    ss = fmaf(val, val, ss);
  }
  const float s2 = block_sum(ss, sScr, t);
  const float var = (s2 - CCH*mean0*mean0) * (1.f/(L2C*CCH));
  const float inv = rsqrtf(var + 1e-5f);

  // ---- SO3Linear 1 (LN folded). Reads sA only, writes disjoint sB rows:
  // no syncs needed between degrees.
  lin1<0>(sA, sB, w1, norm_w, vec0, inv, mean0, t);
  lin1<1>(sA, sB, w1, norm_w, vec0, inv, mean0, t);
  lin1<2>(sA, sB, w1, norm_w, vec0, inv, mean0, t);
  lin1<3>(sA, sB, w1, norm_w, vec0, inv, mean0, t);
  lin1<4>(sA, sB, w1, norm_w, vec0, inv, mean0, t);
  __syncthreads();

  // ---- Gaunt depthwise self-TP on exact reduced grid, in-place on sB
  {
    const int c = t & 127, gg = t >> 7;
    float u[25], y[25];
#pragma unroll
    for (int i = 0; i < 25; ++i) { u[i] = sB[i*PADR + pidx(c)]; y[i] = 0.f; }
    __syncthreads();   // all reads done before partial overwrite
    for (int g = gg*64; g < gg*64 + 64; ++g) {
      const float4* yr = (const float4*)&sY[g*YP];
      float f0 = 0.f, f1 = 0.f, f2 = 0.f, f3 = 0.f;   // 4 indep FMA chains
#pragma unroll
      for (int qq = 0; qq < 6; ++qq) {
        const float4 yv = yr[qq];
        f0 = fmaf(u[4*qq+0], yv.x, f0);
        f1 = fmaf(u[4*qq+1], yv.y, f1);
        f2 = fmaf(u[4*qq+2], yv.z, f2);
        f3 = fmaf(u[4*qq+3], yv.w, f3);
      }
      const float f = ((f0+f1)+(f2+f3)) + u[24]*sY[g*YP + 24];
      const float s = f*f;
      const float4* wr = (const float4*)&sYw[g*YP];
#pragma unroll
      for (int qq = 0; qq < 6; ++qq) {
        const float4 wv = wr[qq];
        y[4*qq+0] = fmaf(s, wv.x, y[4*qq+0]);
        y[4*qq+1] = fmaf(s, wv.y, y[4*qq+1]);
        y[4*qq+2] = fmaf(s, wv.z, y[4*qq+2]);
        y[4*qq+3] = fmaf(s, wv.w, y[4*qq+3]);
      }
      y[24] = fmaf(s, sYw[g*YP + 24], y[24]);
    }
    if (gg == 1) {
#pragma unroll
      for (int i = 0; i < 25; ++i) sB[i*PADR + pidx(c)] = y[i];
    }
    __syncthreads();
    if (gg == 0) {
#pragma unroll
      for (int i = 0; i < 25; ++i)
        sB[i*PADR + pidx(c)] = (y[i] + sB[i*PADR + pidx(c)]) * tp_w[lof_of(i)*CCH + c];
    }
    __syncthreads();
  }

  // ---- SO3Linear 2 + bias(l=0) + residual -> global (no syncs needed)
  lin2<0>(sB, sA, w2, b2, on, t);
  lin2<1>(sB, sA, w2, b2, on, t);
  lin2<2>(sB, sA, w2, b2, on, t);
  lin2<3>(sB, sA, w2, b2, on, t);
  lin2<4>(sB, sA, w2, b2, on, t);
}

extern "C" void kernel_launch(void* const* d_in, const int* in_sizes, int n_in,
                              void* d_out, int out_size, void* d_ws, size_t ws_size,
                              hipStream_t stream) {
  (void)n_in; (void)out_size; (void)ws_size;
  const float* x      = (const float*)d_in[0];
  // d_in[1] = batch (int32) -- only feeds drop_path(rate=0), unused
  const float* norm_w = (const float*)d_in[2];
  const float* norm_b = (const float*)d_in[3];
  const float* w1     = (const float*)d_in[4];
  const float* b1     = (const float*)d_in[5];
  const float* tp_w   = (const float*)d_in[6];
  const float* w2     = (const float*)d_in[7];
  const float* b2     = (const float*)d_in[8];
  float* out  = (float*)d_out;
  float* ytab = (float*)d_ws;   // needs (2*NG*YP + CCH)*4 = 29184 B scratch

  const int N = in_sizes[0] / (L2C*CCH);

  init_tables_kernel<<<dim3(1), dim3(256), 0, stream>>>(ytab, norm_b, w1, b1);
  fused_gaunt_kernel<<<dim3(N), dim3(256), 0, stream>>>(
      x, norm_w, w1, tp_w, w2, b2, ytab, out);
}

// Round 3
// 199.681 us; speedup vs baseline: 1.3967x; 1.3967x over previous
//
#include <hip/hip_runtime.h>
#include <math.h>

#define NTHH 4            // stored theta rows (Gauss-Legendre 8, mirror symmetry)
#define NPHG 16           // uniform phi points (exact for |m| < 16, need <= 12)
#define NROW (NTHH*NPHG)  // 64 stored grid rows (each serves itself + theta-mirror)
#define YP   28           // Y row stride, padded 25->28 for float4 alignment
#define L2C  25
#define CCH  128
#define PADR 144          // padded LDS row stride: 4 quarters x 36 floats

static __device__ __forceinline__ int lof_of(int i) {
  return (i >= 16) ? 4 : (i >= 9) ? 3 : (i >= 4) ? 2 : (i >= 1) ? 1 : 0;
}
static __device__ __forceinline__ int pidx(int c) {   // padded channel index
  return (c >> 5) * 36 + (c & 31);
}

// ---------------------------------------------------------------------------
// Build Y[g][i] table (g = 4 GL-theta rows x 16 phi, stride YP) + wq[4].
// GL-8 nodes/weights hardcoded (compile-time constants; no Newton).
// ws layout: [0, NROW*YP) Y | [NROW*YP, +4) wq = w_t * 2pi/16
// ---------------------------------------------------------------------------
__global__ void init_tables_kernel(float* __restrict__ ws) {
  const double CT[4] = {-0.9602898564975363, -0.7966664774136267,
                        -0.5255324099163290, -0.1834346424956498};
  const double WT[4] = { 0.1012285362903763,  0.2223810344533745,
                         0.3137066458778873,  0.3626837833783620};
  const double PI = 3.14159265358979323846264338327950288;
  const double FACT[9] = {1,1,2,6,24,120,720,5040,40320};
  const int t = threadIdx.x + blockIdx.x * blockDim.x;
  for (int e = t; e < NROW*YP; e += blockDim.x * gridDim.x) {
    const int g = e / YP, i = e % YP;
    float yv = 0.f;
    if (i < L2C) {
      const int tt = g / NPHG, pp = g % NPHG;
      int l = 0; while ((l+1)*(l+1) <= i) ++l;
      const int m = i - l*l - l;
      const int am = m < 0 ? -m : m;
      const double x = CT[tt], st = sqrt(1.0 - x*x);
      double pmm = 1.0;
      for (int mm = 1; mm <= am; ++mm) pmm *= -(2.0*mm - 1.0) * st;
      double plm;
      if (l == am) plm = pmm;
      else {
        double pa = pmm, pb = (2.0*am + 1.0) * x * pmm;
        for (int ll = am + 2; ll <= l; ++ll) {
          double pc = ((2.0*ll - 1.0)*x*pb - (ll + am - 1.0)*pa) / (double)(ll - am);
          pa = pb; pb = pc;
        }
        plm = pb;
      }
      const double Nn = sqrt((2.0*l + 1.0)/(4.0*PI) * FACT[l-am]/FACT[l+am]);
      const double phi = 2.0*PI*pp/NPHG;
      double ang, pref;
      if (m == 0)      { ang = 1.0;          pref = 1.0; }
      else if (m > 0)  { ang = cos(m*phi);   pref = sqrt(2.0); }
      else             { ang = sin(am*phi);  pref = sqrt(2.0); }
      yv = (float)(pref * Nn * plm * ang);
    }
    ws[e] = yv;
  }
  if (t < 4) ws[NROW*YP + t] = (float)(WT[t] * (2.0*PI/NPHG));
}

// block-wide sum over 256 threads (4 waves of 64)
__device__ __forceinline__ float block_sum(float v, float* scr, int t) {
#pragma unroll
  for (int o = 32; o > 0; o >>= 1) v += __shfl_down(v, o, 64);
  __syncthreads();
  if ((t & 63) == 0) scr[t >> 6] = v;
  __syncthreads();
  return scr[0] + scr[1] + scr[2] + scr[3];
}

// ---------------------------------------------------------------------------
// Per-degree SO3 linear, plain GEMV (LN already materialized in sIn).
// 4-way c-split in lane bits 4-5, 2 outputs (d, d+64) per thread,
// shfl_xor(16/32) quarter reduce. FINAL: + bias + global residual -> out.
// ---------------------------------------------------------------------------
template<int L, bool FINAL>
__device__ __forceinline__ void so3lin(const float* __restrict__ sIn,
                                       float* __restrict__ sOut,
                                       const float* __restrict__ W,
                                       const float* __restrict__ bias,
                                       const float* __restrict__ xres,
                                       float* __restrict__ gout, int t) {
  constexpr int NC = 2*L + 1, I0 = L*L;
  const int dlo = (t & 15) | ((t >> 2) & 48);   // lane low bits + wave*16
  const int q   = (t >> 4) & 3;                 // c-quarter = lane bits 4-5
  float acc0[NC], acc1[NC];
#pragma unroll
  for (int j = 0; j < NC; ++j) { acc0[j] = 0.f; acc1[j] = 0.f; }
  const float* w = W + L*CCH*CCH;
  const float* arow0 = sIn + I0*PADR + q*36;
  for (int cc = 0; cc < 32; cc += 4) {
    const float* wc = w + (q*32 + cc)*CCH;
    const float wa0 = wc[dlo],        wb0 = wc[dlo+64];
    const float wa1 = wc[CCH+dlo],    wb1 = wc[CCH+dlo+64];
    const float wa2 = wc[2*CCH+dlo],  wb2 = wc[2*CCH+dlo+64];
    const float wa3 = wc[3*CCH+dlo],  wb3 = wc[3*CCH+dlo+64];
#pragma unroll
    for (int j = 0; j < NC; ++j) {
      const float4 a = *(const float4*)&arow0[j*PADR + cc];
      acc0[j] = fmaf(a.w,wa3, fmaf(a.z,wa2, fmaf(a.y,wa1, fmaf(a.x,wa0, acc0[j]))));
      acc1[j] = fmaf(a.w,wb3, fmaf(a.z,wb2, fmaf(a.y,wb1, fmaf(a.x,wb0, acc1[j]))));
    }
  }
#pragma unroll
  for (int j = 0; j < NC; ++j) {
    acc0[j] += __shfl_xor(acc0[j], 16, 64); acc0[j] += __shfl_xor(acc0[j], 32, 64);
    acc1[j] += __shfl_xor(acc1[j], 16, 64); acc1[j] += __shfl_xor(acc1[j], 32, 64);
  }
  if (q == 0) {
#pragma unroll
    for (int j = 0; j < NC; ++j) {
      float r0 = acc0[j], r1 = acc1[j];
      if (L == 0) { r0 += bias[dlo]; r1 += bias[dlo+64]; }
      if (FINAL) {
        gout[(I0+j)*CCH + dlo]    = r0 + xres[(I0+j)*CCH + dlo];
        gout[(I0+j)*CCH + dlo+64] = r1 + xres[(I0+j)*CCH + dlo+64];
      } else {
        sOut[(I0+j)*PADR + pidx(dlo)]    = r0;
        sOut[(I0+j)*PADR + pidx(dlo+64)] = r1;
      }
    }
  }
}

// ---------------------------------------------------------------------------
// Fused: LN -> Linear1 -> Gaunt self-TP (mirror-folded exact grid) ->
// Linear2 -> +residual.  One block per node. LDS ~36 KB -> 4 blocks/CU.
// ---------------------------------------------------------------------------
__global__ __launch_bounds__(256, 4)
void fused_gaunt_kernel(const float* __restrict__ x,
                        const float* __restrict__ norm_w,
                        const float* __restrict__ norm_b,
                        const float* __restrict__ w1,
                        const float* __restrict__ b1,
                        const float* __restrict__ tp_w,
                        const float* __restrict__ w2,
                        const float* __restrict__ b2,
                        const float* __restrict__ ytab,
                        float* __restrict__ out) {
  __shared__ float sY[NROW*YP];    // 7168 B
  __shared__ float sA[L2C*PADR];   // 14400 B (x, then normalized h in place)
  __shared__ float sB[L2C*PADR];   // 14400 B (lin1 out / TP in place)
  __shared__ float sWq[4];
  __shared__ float sScr[4];

  const int t = threadIdx.x;
  const int n = blockIdx.x;
  const float* xn = x   + (size_t)n * (L2C*CCH);
  float*       on = out + (size_t)n * (L2C*CCH);

  // ---- stage: x -> sA (padded quarters), Y table -> LDS
  for (int e = t; e < (L2C*CCH)/4; e += 256) {
    const int i = e >> 5, c = (e & 31) << 2;
    *(float4*)&sA[i*PADR + pidx(c)] = ((const float4*)xn)[e];
  }
  for (int e = t; e < (NROW*YP)/4; e += 256)
    ((float4*)sY)[e] = ((const float4*)ytab)[e];
  if (t < 4) sWq[t] = ytab[NROW*YP + t];
  __syncthreads();

  // ---- LN statistics
  float v0 = (t < CCH) ? sA[pidx(t)] : 0.f;
  const float mean0 = block_sum(v0, sScr, t) * (1.f/CCH);
  float ss = 0.f;
  for (int e = t; e < L2C*CCH; e += 256) {
    const float val = sA[(e >> 7)*PADR + pidx(e & 127)];
    ss = fmaf(val, val, ss);
  }
  const float s2 = block_sum(ss, sScr, t);
  const float var = (s2 - CCH*mean0*mean0) * (1.f/(L2C*CCH));
  const float inv = rsqrtf(var + 1e-5f);

  // ---- materialize normalized h in place (cheap; keeps linears scale-free)
  for (int e = t; e < L2C*CCH; e += 256) {
    const int i = e >> 7, c = e & 127;
    float val = sA[i*PADR + pidx(c)];
    if (i == 0) val -= mean0;
    val *= inv * norm_w[lof_of(i)*CCH + c];
    if (i == 0) val += norm_b[c];
    sA[i*PADR + pidx(c)] = val;
  }
  __syncthreads();

  // ---- SO3Linear 1 (disjoint sB rows per degree; one sync at end)
  so3lin<0,false>(sA, sB, w1, b1, nullptr, nullptr, t);
  so3lin<1,false>(sA, sB, w1, b1, nullptr, nullptr, t);
  so3lin<2,false>(sA, sB, w1, b1, nullptr, nullptr, t);
  so3lin<3,false>(sA, sB, w1, b1, nullptr, nullptr, t);
  so3lin<4,false>(sA, sB, w1, b1, nullptr, nullptr, t);
  __syncthreads();

  // ---- Gaunt self-TP: 128-point exact grid folded to 64 stored rows.
  // Mirror row (theta -> -theta): Y[g'][i] = sgn_i * Y[g][i], sgn_i=(-1)^(l+|m|),
  // same quadrature weight. y[i] += wq*(s + sgn_i*sm)*Y[g][i].
  {
    const int c = t & 127, gg = t >> 7;
    float u[25], y[25];
#pragma unroll
    for (int i = 0; i < 25; ++i) { u[i] = sB[i*PADR + pidx(c)]; y[i] = 0.f; }
    __syncthreads();   // all u reads complete before sB partial overwrite
#pragma unroll
    for (int tt2 = 0; tt2 < 2; ++tt2) {
      const int r0 = (gg*2 + tt2) * NPHG;
      const float wq = sWq[gg*2 + tt2];
      for (int pp = 0; pp < NPHG; ++pp) {
        const float4* yr = (const float4*)&sY[(r0 + pp)*YP];
        const float4 g0 = yr[0], g1 = yr[1], g2 = yr[2];
        const float4 g3 = yr[3], g4 = yr[4], g5 = yr[5];
        const float y24 = sY[(r0 + pp)*YP + 24];
        // f = u.Y(g);  fm = (sgn*u).Y(g) = u.Y(mirror)  -- signs are free neg-mods
        float f0 =  u[ 0]*g0.x, f1 =  u[ 1]*g0.y, f2 =  u[ 2]*g0.z, f3 =  u[ 3]*g0.w;
        float m0 =  u[ 0]*g0.x, m1 =  u[ 1]*g0.y, m2 = -u[ 2]*g0.z, m3 =  u[ 3]*g0.w;
        f0 = fmaf(u[ 4], g1.x, f0); f1 = fmaf(u[ 5], g1.y, f1);
        f2 = fmaf(u[ 6], g1.z, f2); f3 = fmaf(u[ 7], g1.w, f3);
        m0 = fmaf( u[ 4], g1.x, m0); m1 = fmaf(-u[ 5], g1.y, m1);
        m2 = fmaf( u[ 6], g1.z, m2); m3 = fmaf(-u[ 7], g1.w, m3);
        f0 = fmaf(u[ 8], g2.x, f0); f1 = fmaf(u[ 9], g2.y, f1);
        f2 = fmaf(u[10], g2.z, f2); f3 = fmaf(u[11], g2.w, f3);
        m0 = fmaf( u[ 8], g2.x, m0); m1 = fmaf( u[ 9], g2.y, m1);
        m2 = fmaf(-u[10], g2.z, m2); m3 = fmaf( u[11], g2.w, m3);
        f0 = fmaf(u[12], g3.x, f0); f1 = fmaf(u[13], g3.y, f1);
        f2 = fmaf(u[14], g3.z, f2); f3 = fmaf(u[15], g3.w, f3);
        m0 = fmaf(-u[12], g3.x, m0); m1 = fmaf( u[13], g3.y, m1);
        m2 = fmaf(-u[14], g3.z, m2); m3 = fmaf( u[15], g3.w, m3);
        f0 = fmaf(u[16], g4.x, f0); f1 = fmaf(u[17], g4.y, f1);
        f2 = fmaf(u[18], g4.z, f2); f3 = fmaf(u[19], g4.w, f3);
        m0 = fmaf( u[16], g4.x, m0); m1 = fmaf(-u[17], g4.y, m1);
        m2 = fmaf( u[18], g4.z, m2); m3 = fmaf(-u[19], g4.w, m3);
        f0 = fmaf(u[20], g5.x, f0); f1 = fmaf(u[21], g5.y, f1);
        f2 = fmaf(u[22], g5.z, f2); f3 = fmaf(u[23], g5.w, f3);
        m0 = fmaf( u[20], g5.x, m0); m1 = fmaf(-u[21], g5.y, m1);
        m2 = fmaf( u[22], g5.z, m2); m3 = fmaf(-u[23], g5.w, m3);
        const float f  = ((f0+f1)+(f2+f3)) + u[24]*y24;
        const float fm = ((m0+m1)+(m2+m3)) + u[24]*y24;
        const float s = f*f, sm = fm*fm;
        const float ap = wq*(s + sm), am = wq*(s - sm);
        y[ 0] = fmaf(ap, g0.x, y[ 0]); y[ 1] = fmaf(ap, g0.y, y[ 1]);
        y[ 2] = fmaf(am, g0.z, y[ 2]); y[ 3] = fmaf(ap, g0.w, y[ 3]);
        y[ 4] = fmaf(ap, g1.x, y[ 4]); y[ 5] = fmaf(am, g1.y, y[ 5]);
        y[ 6] = fmaf(ap, g1.z, y[ 6]); y[ 7] = fmaf(am, g1.w, y[ 7]);
        y[ 8] = fmaf(ap, g2.x, y[ 8]); y[ 9] = fmaf(ap, g2.y, y[ 9]);
        y[10] = fmaf(am, g2.z, y[10]); y[11] = fmaf(ap, g2.w, y[11]);
        y[12] = fmaf(am, g3.x, y[12]); y[13] = fmaf(ap, g3.y, y[13]);
        y[14] = fmaf(am, g3.z, y[14]); y[15] = fmaf(ap, g3.w, y[15]);
        y[16] = fmaf(ap, g4.x, y[16]); y[17] = fmaf(am, g4.y, y[17]);
        y[18] = fmaf(ap, g4.z, y[18]); y[19] = fmaf(am, g4.w, y[19]);
        y[20] = fmaf(ap, g5.x, y[20]); y[21] = fmaf(am, g5.y, y[21]);
        y[22] = fmaf(ap, g5.z, y[22]); y[23] = fmaf(am, g5.w, y[23]);
        y[24] = fmaf(ap, y24,  y[24]);
      }
    }
    if (gg == 1) {
#pragma unroll
      for (int i = 0; i < 25; ++i) sB[i*PADR + pidx(c)] = y[i];
    }
    __syncthreads();
    if (gg == 0) {
#pragma unroll
      for (int i = 0; i < 25; ++i)
        sB[i*PADR + pidx(c)] = (y[i] + sB[i*PADR + pidx(c)]) * tp_w[lof_of(i)*CCH + c];
    }
    __syncthreads();
  }

  // ---- SO3Linear 2 + bias(l=0) + residual (global re-read) -> out
  so3lin<0,true>(sB, nullptr, w2, b2, xn, on, t);
  so3lin<1,true>(sB, nullptr, w2, b2, xn, on, t);
  so3lin<2,true>(sB, nullptr, w2, b2, xn, on, t);
  so3lin<3,true>(sB, nullptr, w2, b2, xn, on, t);
  so3lin<4,true>(sB, nullptr, w2, b2, xn, on, t);
}

extern "C" void kernel_launch(void* const* d_in, const int* in_sizes, int n_in,
                              void* d_out, int out_size, void* d_ws, size_t ws_size,
                              hipStream_t stream) {
  (void)n_in; (void)out_size; (void)ws_size;
  const float* x      = (const float*)d_in[0];
  // d_in[1] = batch (int32) -- only feeds drop_path(rate=0), unused
  const float* norm_w = (const float*)d_in[2];
  const float* norm_b = (const float*)d_in[3];
  const float* w1     = (const float*)d_in[4];
  const float* b1     = (const float*)d_in[5];
  const float* tp_w   = (const float*)d_in[6];
  const float* w2     = (const float*)d_in[7];
  const float* b2     = (const float*)d_in[8];
  float* out  = (float*)d_out;
  float* ytab = (float*)d_ws;   // needs (NROW*YP + 4)*4 = 7184 B scratch

  const int N = in_sizes[0] / (L2C*CCH);

  init_tables_kernel<<<dim3(7), dim3(256), 0, stream>>>(ytab);
  fused_gaunt_kernel<<<dim3(N), dim3(256), 0, stream>>>(
      x, norm_w, norm_b, w1, b1, tp_w, w2, b2, ytab, out);
}

// Round 4
// 184.217 us; speedup vs baseline: 1.5140x; 1.0839x over previous
//
#include <hip/hip_runtime.h>

#define NTHH 4            // stored theta rows (GL-8 folded by theta-mirror)
#define NPHH 8            // stored phi cols (16 folded by phi -> phi+pi)
#define NROW (NTHH*NPHH)  // 32 stored grid rows; each serves 4 quadrature points
#define YP   28           // Y row stride, padded 25->28 for float4 alignment
#define L2C  25
#define CCH  128
#define PADR 144          // padded LDS row stride: 4 quarters x 36 floats

static __device__ __host__ __forceinline__ int lof_of(int i) {
  return (i >= 16) ? 4 : (i >= 9) ? 3 : (i >= 4) ? 2 : (i >= 1) ? 1 : 0;
}
static __device__ __forceinline__ int pidx(int c) {   // padded channel index
  return (c >> 5) * 36 + (c & 31);
}

// ---------------------------------------------------------------------------
// Compile-time Y table: Y[g][i] for g = 4 GL-theta rows x 8 phi cols.
// cos/sin(k*pi/8) via constexpr angle-addition from sqrt(1/2); Legendre by
// recurrence; normalization via constexpr Newton sqrt. No init kernel at all.
// ---------------------------------------------------------------------------
static constexpr double csqrt_(double x) {
  double y = x > 1.0 ? x : 1.0;
  for (int i = 0; i < 60; ++i) y = 0.5 * (y + x / y);
  return y;
}

struct alignas(16) YTabT { float y[NROW * YP]; float wq[4]; };

static constexpr YTabT build_ytab() {
  YTabT T{};
  constexpr double CT[4] = {-0.9602898564975363, -0.7966664774136267,
                            -0.5255324099163290, -0.1834346424956498};
  constexpr double WT[4] = { 0.1012285362903763,  0.2223810344533745,
                             0.3137066458778873,  0.3626837833783620};
  constexpr double PI = 3.14159265358979323846264338327950288;
  const double FACT[9] = {1,1,2,6,24,120,720,5040,40320};
  // cos/sin(k*pi/8), k=0..15
  double c8[16] = {}, s8[16] = {};
  {
    const double c2 = csqrt_(0.5);
    const double c1 = csqrt_((1.0 + c2) * 0.5), s1 = csqrt_((1.0 - c2) * 0.5);
    double ck = 1.0, sk = 0.0;
    for (int k = 0; k < 16; ++k) {
      c8[k] = ck; s8[k] = sk;
      const double cn = ck * c1 - sk * s1;
      const double sn = sk * c1 + ck * s1;
      ck = cn; sk = sn;
    }
  }
  const double SQ2 = csqrt_(2.0);
  // normalizations NN[l][am]
  double NN[5][5] = {};
  for (int l = 0; l <= 4; ++l)
    for (int am = 0; am <= l; ++am)
      NN[l][am] = csqrt_((2.0*l + 1.0) / (4.0*PI) * FACT[l-am] / FACT[l+am]);
  for (int g = 0; g < NROW; ++g) {
    const int tt = g / NPHH, pp = g % NPHH;
    const double x = CT[tt], st = csqrt_(1.0 - x*x);
    for (int i = 0; i < L2C; ++i) {
      int l = 0; while ((l+1)*(l+1) <= i) ++l;
      const int m = i - l*l - l, am = m < 0 ? -m : m;
      double pmm = 1.0;
      for (int mm = 1; mm <= am; ++mm) pmm *= -(2.0*mm - 1.0) * st;
      double plm = pmm;
      if (l > am) {
        double pa = pmm, pb = (2.0*am + 1.0) * x * pmm;
        for (int ll = am + 2; ll <= l; ++ll) {
          const double pc = ((2.0*ll - 1.0)*x*pb - (ll + am - 1.0)*pa) / (double)(ll - am);
          pa = pb; pb = pc;
        }
        plm = pb;
      }
      const int k = (am * pp) & 15;          // m*phi = (m*p)*pi/8
      double ang = 1.0, pref = 1.0;
      if (m > 0)      { ang = c8[k]; pref = SQ2; }
      else if (m < 0) { ang = s8[k]; pref = SQ2; }
      T.y[g*YP + i] = (float)(pref * NN[l][am] * plm * ang);
    }
    for (int i = L2C; i < YP; ++i) T.y[g*YP + i] = 0.0f;
  }
  for (int t = 0; t < 4; ++t) T.wq[t] = (float)(WT[t] * (2.0*PI/16.0));
  return T;
}

__device__ constexpr YTabT G_Y = build_ytab();

// block-wide sum over 256 threads (4 waves of 64)
__device__ __forceinline__ float block_sum(float v, float* scr, int t) {
#pragma unroll
  for (int o = 32; o > 0; o >>= 1) v += __shfl_down(v, o, 64);
  __syncthreads();
  if ((t & 63) == 0) scr[t >> 6] = v;
  __syncthreads();
  return scr[0] + scr[1] + scr[2] + scr[3];
}

// ---------------------------------------------------------------------------
// Per-degree SO3 linear GEMV. 4-way c-split in lane bits 4-5, 2 outputs
// (d, d+64) per thread, shfl_xor(16/32) quarter reduce.
// FINAL: + bias + global residual -> out.
// ---------------------------------------------------------------------------
template<int L, bool FINAL>
__device__ __forceinline__ void so3lin(const float* __restrict__ sIn,
                                       float* __restrict__ sOut,
                                       const float* __restrict__ W,
                                       const float* __restrict__ bias,
                                       const float* __restrict__ xres,
                                       float* __restrict__ gout, int t) {
  constexpr int NC = 2*L + 1, I0 = L*L;
  const int dlo = (t & 15) | ((t >> 2) & 48);   // lane low bits + wave*16
  const int q   = (t >> 4) & 3;                 // c-quarter = lane bits 4-5
  float acc0[NC], acc1[NC];
#pragma unroll
  for (int j = 0; j < NC; ++j) { acc0[j] = 0.f; acc1[j] = 0.f; }
  const float* w = W + L*CCH*CCH;
  const float* arow0 = sIn + I0*PADR + q*36;
  for (int cc = 0; cc < 32; cc += 4) {
    const float* wc = w + (q*32 + cc)*CCH;
    const float wa0 = wc[dlo],        wb0 = wc[dlo+64];
    const float wa1 = wc[CCH+dlo],    wb1 = wc[CCH+dlo+64];
    const float wa2 = wc[2*CCH+dlo],  wb2 = wc[2*CCH+dlo+64];
    const float wa3 = wc[3*CCH+dlo],  wb3 = wc[3*CCH+dlo+64];
#pragma unroll
    for (int j = 0; j < NC; ++j) {
      const float4 a = *(const float4*)&arow0[j*PADR + cc];
      acc0[j] = fmaf(a.w,wa3, fmaf(a.z,wa2, fmaf(a.y,wa1, fmaf(a.x,wa0, acc0[j]))));
      acc1[j] = fmaf(a.w,wb3, fmaf(a.z,wb2, fmaf(a.y,wb1, fmaf(a.x,wb0, acc1[j]))));
    }
  }
#pragma unroll
  for (int j = 0; j < NC; ++j) {
    acc0[j] += __shfl_xor(acc0[j], 16, 64); acc0[j] += __shfl_xor(acc0[j], 32, 64);
    acc1[j] += __shfl_xor(acc1[j], 16, 64); acc1[j] += __shfl_xor(acc1[j], 32, 64);
  }
  if (q == 0) {
#pragma unroll
    for (int j = 0; j < NC; ++j) {
      float r0 = acc0[j], r1 = acc1[j];
      if (L == 0) { r0 += bias[dlo]; r1 += bias[dlo+64]; }
      if (FINAL) {
        gout[(I0+j)*CCH + dlo]    = r0 + xres[(I0+j)*CCH + dlo];
        gout[(I0+j)*CCH + dlo+64] = r1 + xres[(I0+j)*CCH + dlo+64];
      } else {
        sOut[(I0+j)*PADR + pidx(dlo)]    = r0;
        sOut[(I0+j)*PADR + pidx(dlo+64)] = r1;
      }
    }
  }
}

// ---------------------------------------------------------------------------
// Fused: LN -> Linear1 -> Gaunt self-TP (theta+phi folded exact grid) ->
// Linear2 -> +residual.  One block per node. LDS ~32.4 KB.
// ---------------------------------------------------------------------------
__global__ __launch_bounds__(256, 5)
void fused_gaunt_kernel(const float* __restrict__ x,
                        const float* __restrict__ norm_w,
                        const float* __restrict__ norm_b,
                        const float* __restrict__ w1,
                        const float* __restrict__ b1,
                        const float* __restrict__ tp_w,
                        const float* __restrict__ w2,
                        const float* __restrict__ b2,
                        float* __restrict__ out) {
  __shared__ float sY[NROW*YP];    // 3584 B
  __shared__ float sA[L2C*PADR];   // 14400 B (x, then normalized h in place)
  __shared__ float sB[L2C*PADR];   // 14400 B (lin1 out / TP in place)
  __shared__ float sScr[4];

  const int t = threadIdx.x;
  const int n = blockIdx.x;
  const float* xn = x   + (size_t)n * (L2C*CCH);
  float*       on = out + (size_t)n * (L2C*CCH);

  // ---- stage: x -> sA (padded quarters), Y table -> LDS
  for (int e = t; e < (L2C*CCH)/4; e += 256) {
    const int i = e >> 5, c = (e & 31) << 2;
    *(float4*)&sA[i*PADR + pidx(c)] = ((const float4*)xn)[e];
  }
  if (t < (NROW*YP)/4) ((float4*)sY)[t] = ((const float4*)G_Y.y)[t];
  __syncthreads();

  // ---- LN statistics
  float v0 = (t < CCH) ? sA[pidx(t)] : 0.f;
  const float mean0 = block_sum(v0, sScr, t) * (1.f/CCH);
  float ss = 0.f;
  for (int e = t; e < L2C*CCH; e += 256) {
    const float val = sA[(e >> 7)*PADR + pidx(e & 127)];
    ss = fmaf(val, val, ss);
  }
  const float s2 = block_sum(ss, sScr, t);
  const float var = (s2 - CCH*mean0*mean0) * (1.f/(L2C*CCH));
  const float inv = rsqrtf(var + 1e-5f);

  // ---- materialize normalized h in place
  for (int e = t; e < L2C*CCH; e += 256) {
    const int i = e >> 7, c = e & 127;
    float val = sA[i*PADR + pidx(c)];
    if (i == 0) val -= mean0;
    val *= inv * norm_w[lof_of(i)*CCH + c];
    if (i == 0) val += norm_b[c];
    sA[i*PADR + pidx(c)] = val;
  }
  __syncthreads();

  // ---- SO3Linear 1 (disjoint sB rows per degree; one sync at end)
  so3lin<0,false>(sA, sB, w1, b1, nullptr, nullptr, t);
  so3lin<1,false>(sA, sB, w1, b1, nullptr, nullptr, t);
  so3lin<2,false>(sA, sB, w1, b1, nullptr, nullptr, t);
  so3lin<3,false>(sA, sB, w1, b1, nullptr, nullptr, t);
  so3lin<4,false>(sA, sB, w1, b1, nullptr, nullptr, t);
  __syncthreads();

  // ---- Gaunt self-TP: 128-point exact grid, folded 4x by theta-mirror
  // (sgn_i = (-1)^(l+|m|)) and phi->phi+pi (sig_i = (-1)^|m|).
  // Classes: A(+,+)={0,4,6,8,16,18,20,22,24} B(+,-)={1,3,9,11,13,15}
  //          C(-,+)={2,10,12,14}             D(-,-)={5,7,17,19,21,23}
  // f(+t,p)=A+B+C+D  f(+t,p+8)=A-B+C-D  f(-t,p)=A+B-C-D  f(-t,p+8)=A-B-C+D
  {
    const int c = t & 127, gg = t >> 7;
    float u[25], y[25];
#pragma unroll
    for (int i = 0; i < 25; ++i) { u[i] = sB[i*PADR + pidx(c)]; y[i] = 0.f; }
    __syncthreads();   // all u reads complete before sB partial overwrite
#pragma unroll
    for (int tt2 = 0; tt2 < 2; ++tt2) {
      const int tt = gg*2 + tt2;
      const float wq = G_Y.wq[tt];
      for (int pp = 0; pp < NPHH; ++pp) {
        const float4* yr = (const float4*)&sY[(tt*NPHH + pp)*YP];
        const float4 g0 = yr[0], g1 = yr[1], g2 = yr[2];
        const float4 g3 = yr[3], g4 = yr[4], g5 = yr[5];
        const float y24 = sY[(tt*NPHH + pp)*YP + 24];
        // class partial dot-products (A split for ILP)
        float A0 = u[ 0]*g0.x;
        A0 = fmaf(u[ 4], g1.x, A0); A0 = fmaf(u[ 6], g1.z, A0);
        A0 = fmaf(u[ 8], g2.x, A0); A0 = fmaf(u[24], y24,  A0);
        float A1 = u[16]*g4.x;
        A1 = fmaf(u[18], g4.z, A1); A1 = fmaf(u[20], g5.x, A1);
        A1 = fmaf(u[22], g5.z, A1);
        float B = u[ 1]*g0.y;
        B = fmaf(u[ 3], g0.w, B); B = fmaf(u[ 9], g2.y, B);
        B = fmaf(u[11], g2.w, B); B = fmaf(u[13], g3.y, B);
        B = fmaf(u[15], g3.w, B);
        float C = u[ 2]*g0.z;
        C = fmaf(u[10], g2.z, C); C = fmaf(u[12], g3.x, C);
        C = fmaf(u[14], g3.z, C);
        float D = u[ 5]*g1.y;
        D = fmaf(u[ 7], g1.w, D); D = fmaf(u[17], g4.y, D);
        D = fmaf(u[19], g4.w, D); D = fmaf(u[21], g5.y, D);
        D = fmaf(u[23], g5.w, D);
        const float A  = A0 + A1;
        const float tp = A + B, tm = A - B, up = C + D, um = C - D;
        const float f1 = tp + up, f3 = tp - up;   // (+t,p), (-t,p)
        const float f2 = tm + um, f4 = tm - um;   // (+t,p+8), (-t,p+8)
        const float s1 = f1*f1, s2v = f2*f2, s3 = f3*f3, s4 = f4*f4;
        const float p = s1 + s2v, q = s1 - s2v, r = s3 + s4, t4 = s3 - s4;
        const float cA = wq*(p + r), cC = wq*(p - r);
        const float cB = wq*(q + t4), cD = wq*(q - t4);
        y[ 0] = fmaf(cA, g0.x, y[ 0]); y[ 1] = fmaf(cB, g0.y, y[ 1]);
        y[ 2] = fmaf(cC, g0.z, y[ 2]); y[ 3] = fmaf(cB, g0.w, y[ 3]);
        y[ 4] = fmaf(cA, g1.x, y[ 4]); y[ 5] = fmaf(cD, g1.y, y[ 5]);
        y[ 6] = fmaf(cA, g1.z, y[ 6]); y[ 7] = fmaf(cD, g1.w, y[ 7]);
        y[ 8] = fmaf(cA, g2.x, y[ 8]); y[ 9] = fmaf(cB, g2.y, y[ 9]);
        y[10] = fmaf(cC, g2.z, y[10]); y[11] = fmaf(cB, g2.w, y[11]);
        y[12] = fmaf(cC, g3.x, y[12]); y[13] = fmaf(cB, g3.y, y[13]);
        y[14] = fmaf(cC, g3.z, y[14]); y[15] = fmaf(cB, g3.w, y[15]);
        y[16] = fmaf(cA, g4.x, y[16]); y[17] = fmaf(cD, g4.y, y[17]);
        y[18] = fmaf(cA, g4.z, y[18]); y[19] = fmaf(cD, g4.w, y[19]);
        y[20] = fmaf(cA, g5.x, y[20]); y[21] = fmaf(cD, g5.y, y[21]);
        y[22] = fmaf(cA, g5.z, y[22]); y[23] = fmaf(cD, g5.w, y[23]);
        y[24] = fmaf(cA, y24,  y[24]);
      }
    }
    if (gg == 1) {
#pragma unroll
      for (int i = 0; i < 25; ++i) sB[i*PADR + pidx(c)] = y[i];
    }
    __syncthreads();
    if (gg == 0) {
#pragma unroll
      for (int i = 0; i < 25; ++i)
        sB[i*PADR + pidx(c)] = (y[i] + sB[i*PADR + pidx(c)]) * tp_w[lof_of(i)*CCH + c];
    }
    __syncthreads();
  }

  // ---- SO3Linear 2 + bias(l=0) + residual (global re-read) -> out
  so3lin<0,true>(sB, nullptr, w2, b2, xn, on, t);
  so3lin<1,true>(sB, nullptr, w2, b2, xn, on, t);
  so3lin<2,true>(sB, nullptr, w2, b2, xn, on, t);
  so3lin<3,true>(sB, nullptr, w2, b2, xn, on, t);
  so3lin<4,true>(sB, nullptr, w2, b2, xn, on, t);
}

extern "C" void kernel_launch(void* const* d_in, const int* in_sizes, int n_in,
                              void* d_out, int out_size, void* d_ws, size_t ws_size,
                              hipStream_t stream) {
  (void)n_in; (void)out_size; (void)d_ws; (void)ws_size;
  const float* x      = (const float*)d_in[0];
  // d_in[1] = batch (int32) -- only feeds drop_path(rate=0), unused
  const float* norm_w = (const float*)d_in[2];
  const float* norm_b = (const float*)d_in[3];
  const float* w1     = (const float*)d_in[4];
  const float* b1     = (const float*)d_in[5];
  const float* tp_w   = (const float*)d_in[6];
  const float* w2     = (const float*)d_in[7];
  const float* b2     = (const float*)d_in[8];
  float* out  = (float*)d_out;

  const int N = in_sizes[0] / (L2C*CCH);

  fused_gaunt_kernel<<<dim3(N), dim3(256), 0, stream>>>(
      x, norm_w, norm_b, w1, b1, tp_w, w2, b2, out);
}